// Round 9
// baseline (77.126 us; speedup 1.0000x reference)
//
#include <hip/hip_runtime.h>

// OuterProductMean on MI355X (gfx950).
// out[i,j,p] = b2[p] + sum_{c,d} W2[p, c*32+d] * x[i,d] * x[j,c],  x = seq@W1^T + b1.
// Factored: Y[i][c][p] = sum_d W2[p][c*32+d] * x[i][d]  (f16, 2 MB scratch)
//           out[i,j,p] = b2[p] + sum_c x[j,c] * Y[i][c][p]
// TWO kernels only (graph-node gaps cost ~2-3us each):
//   k_xy : fused proj1 + Y. Each block recomputes its 16-row x-chunk (f32,
//          redundant x32 across c-blocks but seq/W1 are L2/L3-resident).
//   k_outer: v_mfma_f32_32x32x16_f16, wave-private LDS-transpose epilogue
//          (NO in-loop barriers; scatter->readback is intra-wave), dense
//          dwordx4 stores, lgkm-only block barriers (2 per block).
// Floor: 67 MB output write ~10.6 us.

static constexpr int LL  = 512;
static constexpr int IND = 256;
static constexpr int DM  = 32;   // DIM_MSA
static constexpr int PD  = 64;   // PAIR_DIM

typedef _Float16 f16x8 __attribute__((ext_vector_type(8)));
typedef float    f32x16 __attribute__((ext_vector_type(16)));

// LDS-only barrier: order ds ops across waves WITHOUT draining global stores.
#define LGKM_BARRIER() do { \
    asm volatile("s_waitcnt lgkmcnt(0)" ::: "memory"); \
    __builtin_amdgcn_s_barrier(); \
  } while (0)

// ---------------- k_xy: fused  x = seq@W1^T + b1  and  Y[i][c][p].
// Grid 1024 = (ic 0..31 i-chunks of 16 rows) x (c 0..31). 128 threads.
__global__ __launch_bounds__(128) void k_xy(const float* __restrict__ seq,
                                            const float* __restrict__ W1,
                                            const float* __restrict__ b1,
                                            const float* __restrict__ W2,
                                            _Float16* __restrict__ xgh,
                                            _Float16* __restrict__ Ygh) {
  __shared__ __align__(16) float seqs[16][260];  // 16.25 KB (pad 4: bank-clean)
  __shared__ __align__(16) float ws2[64][36];    //  9 KB
  __shared__ __align__(16) float xs[16][36];     //  2.25 KB
  const int c     = blockIdx.x & 31;
  const int ibase = (blockIdx.x >> 5) * 16;
  const int t     = threadIdx.x;

  // stage seq rows [16][256]: 1024 float4, coalesced
#pragma unroll
  for (int k = 0; k < 8; ++k) {
    const int idx = t + k * 128;
    const int row = idx >> 6, j4 = idx & 63;
    const float4 v = *(const float4*)(seq + (size_t)(ibase + row) * IND + j4 * 4);
    *(float4*)&seqs[row][j4 * 4] = v;
  }
  // stage W2 slice [64 p][32 d] at column block c
#pragma unroll
  for (int k = 0; k < 4; ++k) {
    const int idx = t + k * 128;
    const int p = idx >> 3, d4 = idx & 7;
    const float4 v = *(const float4*)(W2 + (size_t)p * (DM * DM) + c * DM + d4 * 4);
    *(float4*)&ws2[p][d4 * 4] = v;
  }
  __syncthreads();

  // ---- phase A: x rows (f32). thread: row = t>>3, d = (t&7)*4 .. +4
  {
    const int row = t >> 3, d0 = (t & 7) * 4;
    float a0 = b1[d0], a1 = b1[d0 + 1], a2 = b1[d0 + 2], a3 = b1[d0 + 3];
#pragma unroll 4
    for (int k4 = 0; k4 < 64; ++k4) {
      const float4 s = *(const float4*)&seqs[row][k4 * 4];
      const float4 w0 = *(const float4*)(W1 + (size_t)(d0 + 0) * IND + k4 * 4);
      const float4 w1 = *(const float4*)(W1 + (size_t)(d0 + 1) * IND + k4 * 4);
      const float4 w2 = *(const float4*)(W1 + (size_t)(d0 + 2) * IND + k4 * 4);
      const float4 w3 = *(const float4*)(W1 + (size_t)(d0 + 3) * IND + k4 * 4);
      a0 = fmaf(s.x, w0.x, fmaf(s.y, w0.y, fmaf(s.z, w0.z, fmaf(s.w, w0.w, a0))));
      a1 = fmaf(s.x, w1.x, fmaf(s.y, w1.y, fmaf(s.z, w1.z, fmaf(s.w, w1.w, a1))));
      a2 = fmaf(s.x, w2.x, fmaf(s.y, w2.y, fmaf(s.z, w2.z, fmaf(s.w, w2.w, a2))));
      a3 = fmaf(s.x, w3.x, fmaf(s.y, w3.y, fmaf(s.z, w3.z, fmaf(s.w, w3.w, a3))));
    }
    xs[row][d0 + 0] = a0; xs[row][d0 + 1] = a1;
    xs[row][d0 + 2] = a2; xs[row][d0 + 3] = a3;
    if (c == 0) {   // one c-block per chunk publishes x as f16 for k_outer
      _Float16* xr = xgh + (size_t)(ibase + row) * DM + d0;
      xr[0] = (_Float16)a0; xr[1] = (_Float16)a1;
      xr[2] = (_Float16)a2; xr[3] = (_Float16)a3;
    }
  }
  __syncthreads();

  // ---- phase B: Y[i][c][p] = sum_d ws2[p][d] * xs[i][d], f16 out
  {
    const int p = t & 63, ih = t >> 6;
    float wv[DM];
#pragma unroll
    for (int q = 0; q < 8; ++q) {
      const float4 v = *(const float4*)&ws2[p][q * 4];
      wv[q * 4 + 0] = v.x; wv[q * 4 + 1] = v.y;
      wv[q * 4 + 2] = v.z; wv[q * 4 + 3] = v.w;
    }
#pragma unroll
    for (int il = 0; il < 8; ++il) {
      const int row = ih * 8 + il;
      float a = 0.f;
#pragma unroll
      for (int q = 0; q < 8; ++q) {
        const float4 v = *(const float4*)&xs[row][q * 4];
        a = fmaf(wv[q * 4 + 0], v.x, a);
        a = fmaf(wv[q * 4 + 1], v.y, a);
        a = fmaf(wv[q * 4 + 2], v.z, a);
        a = fmaf(wv[q * 4 + 3], v.w, a);
      }
      Ygh[((size_t)(ibase + row) * DM + c) * PD + p] = (_Float16)a;  // coalesced
    }
  }
}

// ---------------- k_outer: MFMA + wave-private LDS-transpose epilogue.
// Block = 128 thr (2 waves), 2 i-tiles (i0, i0+256) x 128 j x 64 p.
// D layout: col(p)=lane&31, row(j)=(reg&3)+8*(reg>>2)+4*(lane>>5)  [verified R6].
// Each wave transposes its own p-half in a private 4KB obuf -> no in-loop
// barriers; stores are dense dwordx4 (8 x 128B segments per wave-inst).
static constexpr int XPAD = 40;  // f16 row stride 80B (16B-aligned b128 reads)

__global__ __launch_bounds__(128, 3) void k_outer(const _Float16* __restrict__ xgh,
                                                  const _Float16* __restrict__ Ygh,
                                                  const float* __restrict__ b2,
                                                  float* __restrict__ out) {
  __shared__ __align__(16) _Float16 xbs[128 * XPAD];  // 10 KB: [j_local][c]
  __shared__ __align__(16) _Float16 ybs[2 * DM * PD]; // 2 x 4 KB: [c][p]
  __shared__ __align__(16) float    obuf[2][32 * 32]; // per-wave 4 KB
  const int q  = blockIdx.x & 3;       // j-quarter
  const int i0 = blockIdx.x >> 2;      // first i; second is i0+256
  const int t  = threadIdx.x;

  const int lane = t & 63;
  const int w    = t >> 6;        // p-half (0/1)
  const int l31  = lane & 31;
  const int lh   = lane >> 5;
  const int pn   = w * 32 + l31;  // this lane's p (n index)
  float* const obufW = &obuf[w][0];
  const float4 bias4 = *(const float4*)(b2 + w * 32 + (lane & 7) * 4);

  // stage x rows (row j = t): 64B per thread, coalesced; q-dependent only
  {
    const f16x8* src = (const f16x8*)(xgh + (size_t)(q * 128 + t) * DM);
    _Float16* dst = &xbs[t * XPAD];
    *(f16x8*)(dst)      = src[0];
    *(f16x8*)(dst + 8)  = src[1];
    *(f16x8*)(dst + 16) = src[2];
    *(f16x8*)(dst + 24) = src[3];
  }
  // stage Ygh[i0] into ybs[0]
  {
    const f16x8* ys = (const f16x8*)(Ygh + (size_t)i0 * (DM * PD));
    *(f16x8*)&ybs[t * 8]        = ys[t];
    *(f16x8*)&ybs[1024 + t * 8] = ys[128 + t];
  }
  LGKM_BARRIER();

  // issue-early: Ygh[i1] global loads in flight across tile-0 compute
  const f16x8* ys1 = (const f16x8*)(Ygh + (size_t)(i0 + 256) * (DM * PD));
  const f16x8 n0 = ys1[t];
  const f16x8 n1 = ys1[128 + t];

  auto process = [&](int i, const _Float16* __restrict__ yb) {
    // B frags: one-time scattered u16 gather (2-way bank alias = free)
    f16x8 b0, b1;
#pragma unroll
    for (int e = 0; e < 8; ++e) {
      b0[e] = yb[(lh * 8 + e) * PD + pn];
      b1[e] = yb[(16 + lh * 8 + e) * PD + pn];
    }
    const size_t orow0 = ((size_t)i * LL + q * 128) * PD;
#pragma unroll
    for (int jt = 0; jt < 4; ++jt) {
      const int ai = (jt * 32 + l31) * XPAD + lh * 8;
      const f16x8 a0 = *(const f16x8*)&xbs[ai];
      const f16x8 a1 = *(const f16x8*)&xbs[ai + 16];
      f32x16 acc = {};
      acc = __builtin_amdgcn_mfma_f32_32x32x16_f16(a0, b0, acc, 0, 0, 0);
      acc = __builtin_amdgcn_mfma_f32_32x32x16_f16(a1, b1, acc, 0, 0, 0);
      // wave-private transpose: scatter (banks = l31, 2-way max)
#pragma unroll
      for (int r = 0; r < 16; ++r) {
        const int row = (r & 3) + 8 * (r >> 2) + 4 * lh;  // j within subtile
        obufW[row * 32 + l31] = acc[r];
      }
      // intra-wave readback (compiler orders via lgkmcnt) + dense stores
#pragma unroll
      for (int k = 0; k < 4; ++k) {
        const int idx = lane + k * 64;           // float4 idx 0..255
        const int row = idx >> 3, pseg = idx & 7;
        float4 v = *(const float4*)&obufW[idx * 4];
        v.x += bias4.x; v.y += bias4.y; v.z += bias4.z; v.w += bias4.w;
        *(float4*)(out + orow0 + (size_t)(jt * 32 + row) * PD + w * 32 + pseg * 4) = v;
      }
    }
  };

  process(i0, ybs);

  // write-late: commit prefetched Y[i1]
  *(f16x8*)&ybs[2048 + t * 8]        = n0;
  *(f16x8*)&ybs[2048 + 1024 + t * 8] = n1;
  LGKM_BARRIER();

  process(i0 + 256, ybs + 2048);
}

extern "C" void kernel_launch(void* const* d_in, const int* in_sizes, int n_in,
                              void* d_out, int out_size, void* d_ws, size_t ws_size,
                              hipStream_t stream) {
  const float* seq = (const float*)d_in[0];
  const float* W1  = (const float*)d_in[1];
  const float* b1  = (const float*)d_in[2];
  const float* W2  = (const float*)d_in[3];
  const float* b2  = (const float*)d_in[4];
  float* out = (float*)d_out;

  // ws layout: xgh f16[512*32] | Ygh f16[512*32*64]  => ~2.1 MB
  _Float16* xgh = (_Float16*)d_ws;
  _Float16* Ygh = xgh + LL * DM;

  k_xy<<<LL * 2, 128, 0, stream>>>(seq, W1, b1, W2, xgh, Ygh);
  k_outer<<<LL * 2, 128, 0, stream>>>(xgh, Ygh, b2, out);
}

// Round 10
// 27.364 us; speedup vs baseline: 2.8186x; 2.8186x over previous
//
#include <hip/hip_runtime.h>

// OuterProductMean on MI355X (gfx950).
// out[i,j,p] = b2[p] + sum_{c,d} W2[p, c*32+d] * x[i,d] * x[j,c],  x = seq@W1^T + b1.
// Factored: Y[i][c][p] = sum_d W2[p][c*32+d] * x[i][d]  (f16, 2 MB scratch)
//           out[i,j,p] = b2[p] + sum_c x[j,c] * Y[i][c][p]
// Structure: 3 kernels. R9's fused k_xy regressed 20x (W1 global-scatter,
// latency-serialized) -> reverted to R8's k1/k2. k_outer keeps R9's wins:
// wave-private LDS-transpose epilogue (NO in-loop barriers), dense dwordx4
// stores, lgkm-only block barriers, double-buffered Y prefetch.
// Floor: 67 MB output write ~10.6 us; k_outer inferred ~11-12 us in R9.

static constexpr int LL  = 512;
static constexpr int IND = 256;
static constexpr int DM  = 32;   // DIM_MSA
static constexpr int PD  = 64;   // PAIR_DIM

typedef _Float16 f16x8 __attribute__((ext_vector_type(8)));
typedef float    f32x16 __attribute__((ext_vector_type(16)));

// LDS-only barrier: order ds ops across waves WITHOUT draining global stores.
#define LGKM_BARRIER() do { \
    asm volatile("s_waitcnt lgkmcnt(0)" ::: "memory"); \
    __builtin_amdgcn_s_barrier(); \
  } while (0)

// ---------------- k1: x = seq @ W1^T + b1 -> xg f32 [512][32], xgh f16 [512][32]
__global__ __launch_bounds__(256) void k_proj1(const float* __restrict__ seq,
                                               const float* __restrict__ W1,
                                               const float* __restrict__ b1,
                                               float* __restrict__ xg,
                                               _Float16* __restrict__ xgh) {
  __shared__ float part[8][DM];
  const int i   = blockIdx.x;
  const int t   = threadIdx.x;
  const int d   = t & 31;
  const int seg = t >> 5;
  const float* srow = seq + (size_t)i * IND + seg * 32;
  const float* wrow = W1  + (size_t)d * IND + seg * 32;
  float acc = 0.f;
#pragma unroll
  for (int k = 0; k < 32; k += 4) {
    const float4 s4 = *(const float4*)(srow + k);
    const float4 w4 = *(const float4*)(wrow + k);
    acc = fmaf(s4.x, w4.x, acc);
    acc = fmaf(s4.y, w4.y, acc);
    acc = fmaf(s4.z, w4.z, acc);
    acc = fmaf(s4.w, w4.w, acc);
  }
  part[seg][d] = acc;
  __syncthreads();
  if (t < DM) {
    float s = b1[t];
#pragma unroll
    for (int g = 0; g < 8; ++g) s += part[g][t];
    xg[i * DM + t]  = s;
    xgh[i * DM + t] = (_Float16)s;
  }
}

// ---------------- k2: Ygh[i][c][p] = (f16) sum_d W2[p][c*32+d] * x[i][d]
// Grid: 32 c-blocks x 8 i-chunks of 64. Coalesced reads via LDS staging;
// output stores are contiguous 128B u16 wave-stores (p fastest).
__global__ __launch_bounds__(256) void k_y(const float* __restrict__ xg,
                                           const float* __restrict__ W2,
                                           _Float16* __restrict__ Ygh) {
  __shared__ __align__(16) float xs[64][36];
  __shared__ __align__(16) float ws2[64][36];
  const int c     = blockIdx.x & 31;
  const int ibase = (blockIdx.x >> 5) * 64;
  const int t     = threadIdx.x;
#pragma unroll
  for (int k = 0; k < 2; ++k) {
    const int idx = t + k * 256;
    const int il = idx >> 3, d4 = idx & 7;
    const float4 v = *(const float4*)(xg + (size_t)(ibase + il) * DM + d4 * 4);
    *(float4*)&xs[il][d4 * 4] = v;
  }
#pragma unroll
  for (int k = 0; k < 2; ++k) {
    const int idx = t + k * 256;
    const int p = idx >> 3, d4 = idx & 7;
    const float4 v = *(const float4*)(W2 + (size_t)p * (DM * DM) + c * DM + d4 * 4);
    *(float4*)&ws2[p][d4 * 4] = v;
  }
  __syncthreads();
  const int p  = t & 63;
  const int ig = t >> 6;
  float wv[DM];
#pragma unroll
  for (int q = 0; q < 8; ++q) {
    const float4 v = *(const float4*)&ws2[p][q * 4];
    wv[q * 4 + 0] = v.x; wv[q * 4 + 1] = v.y;
    wv[q * 4 + 2] = v.z; wv[q * 4 + 3] = v.w;
  }
#pragma unroll
  for (int il = 0; il < 16; ++il) {
    const int row = ig * 16 + il;
    float a = 0.f;
#pragma unroll
    for (int q = 0; q < 8; ++q) {
      const float4 v = *(const float4*)&xs[row][q * 4];
      a = fmaf(wv[q * 4 + 0], v.x, a);
      a = fmaf(wv[q * 4 + 1], v.y, a);
      a = fmaf(wv[q * 4 + 2], v.z, a);
      a = fmaf(wv[q * 4 + 3], v.w, a);
    }
    Ygh[((size_t)(ibase + row) * DM + c) * PD + p] = (_Float16)a;  // coalesced
  }
}

// ---------------- k_outer: MFMA + wave-private LDS-transpose epilogue.
// Block = 128 thr (2 waves), 2 i-tiles (i0, i0+256) x 128 j x 64 p.
// D layout: col(p)=lane&31, row(j)=(reg&3)+8*(reg>>2)+4*(lane>>5)  [verified R6].
// Each wave transposes its own p-half in a private 4KB obuf -> no in-loop
// barriers; stores are dense dwordx4 (8 x 128B segments per wave-inst).
static constexpr int XPAD = 40;  // f16 row stride 80B (16B-aligned b128 reads)

__global__ __launch_bounds__(128, 3) void k_outer(const _Float16* __restrict__ xgh,
                                                  const _Float16* __restrict__ Ygh,
                                                  const float* __restrict__ b2,
                                                  float* __restrict__ out) {
  __shared__ __align__(16) _Float16 xbs[128 * XPAD];  // 10 KB: [j_local][c]
  __shared__ __align__(16) _Float16 ybs[2 * DM * PD]; // 2 x 4 KB: [c][p]
  __shared__ __align__(16) float    obuf[2][32 * 32]; // per-wave 4 KB
  const int q  = blockIdx.x & 3;       // j-quarter
  const int i0 = blockIdx.x >> 2;      // first i; second is i0+256
  const int t  = threadIdx.x;

  const int lane = t & 63;
  const int w    = t >> 6;        // p-half (0/1)
  const int l31  = lane & 31;
  const int lh   = lane >> 5;
  const int pn   = w * 32 + l31;  // this lane's p (n index)
  float* const obufW = &obuf[w][0];
  const float4 bias4 = *(const float4*)(b2 + w * 32 + (lane & 7) * 4);

  // stage x rows (row j = t): 64B per thread, coalesced; q-dependent only
  {
    const f16x8* src = (const f16x8*)(xgh + (size_t)(q * 128 + t) * DM);
    _Float16* dst = &xbs[t * XPAD];
    *(f16x8*)(dst)      = src[0];
    *(f16x8*)(dst + 8)  = src[1];
    *(f16x8*)(dst + 16) = src[2];
    *(f16x8*)(dst + 24) = src[3];
  }
  // stage Ygh[i0] into ybs[0]
  {
    const f16x8* ys = (const f16x8*)(Ygh + (size_t)i0 * (DM * PD));
    *(f16x8*)&ybs[t * 8]        = ys[t];
    *(f16x8*)&ybs[1024 + t * 8] = ys[128 + t];
  }
  LGKM_BARRIER();

  // issue-early: Ygh[i1] global loads in flight across tile-0 compute
  const f16x8* ys1 = (const f16x8*)(Ygh + (size_t)(i0 + 256) * (DM * PD));
  const f16x8 n0 = ys1[t];
  const f16x8 n1 = ys1[128 + t];

  auto process = [&](int i, const _Float16* __restrict__ yb) {
    // B frags: one-time scattered u16 gather (2-way bank alias = free)
    f16x8 b0, b1;
#pragma unroll
    for (int e = 0; e < 8; ++e) {
      b0[e] = yb[(lh * 8 + e) * PD + pn];
      b1[e] = yb[(16 + lh * 8 + e) * PD + pn];
    }
    const size_t orow0 = ((size_t)i * LL + q * 128) * PD;
#pragma unroll
    for (int jt = 0; jt < 4; ++jt) {
      const int ai = (jt * 32 + l31) * XPAD + lh * 8;
      const f16x8 a0 = *(const f16x8*)&xbs[ai];
      const f16x8 a1 = *(const f16x8*)&xbs[ai + 16];
      f32x16 acc = {};
      acc = __builtin_amdgcn_mfma_f32_32x32x16_f16(a0, b0, acc, 0, 0, 0);
      acc = __builtin_amdgcn_mfma_f32_32x32x16_f16(a1, b1, acc, 0, 0, 0);
      // wave-private transpose: scatter (banks = l31, 2-way max)
#pragma unroll
      for (int r = 0; r < 16; ++r) {
        const int row = (r & 3) + 8 * (r >> 2) + 4 * lh;  // j within subtile
        obufW[row * 32 + l31] = acc[r];
      }
      // intra-wave readback (compiler orders via lgkmcnt) + dense stores
#pragma unroll
      for (int k = 0; k < 4; ++k) {
        const int idx = lane + k * 64;           // float4 idx 0..255
        const int row = idx >> 3, pseg = idx & 7;
        float4 v = *(const float4*)&obufW[idx * 4];
        v.x += bias4.x; v.y += bias4.y; v.z += bias4.z; v.w += bias4.w;
        *(float4*)(out + orow0 + (size_t)(jt * 32 + row) * PD + w * 32 + pseg * 4) = v;
      }
    }
  };

  process(i0, ybs);

  // write-late: commit prefetched Y[i1]
  *(f16x8*)&ybs[2048 + t * 8]        = n0;
  *(f16x8*)&ybs[2048 + 1024 + t * 8] = n1;
  LGKM_BARRIER();

  process(i0 + 256, ybs + 2048);
}

extern "C" void kernel_launch(void* const* d_in, const int* in_sizes, int n_in,
                              void* d_out, int out_size, void* d_ws, size_t ws_size,
                              hipStream_t stream) {
  const float* seq = (const float*)d_in[0];
  const float* W1  = (const float*)d_in[1];
  const float* b1  = (const float*)d_in[2];
  const float* W2  = (const float*)d_in[3];
  const float* b2  = (const float*)d_in[4];
  float* out = (float*)d_out;

  // ws layout: xg f32[512*32] | xgh f16[512*32] | Ygh f16[512*32*64]  => ~2.2 MB
  float* xg     = (float*)d_ws;
  _Float16* xgh = (_Float16*)(xg + LL * DM);
  _Float16* Ygh = (_Float16*)(xg + LL * DM + LL * DM / 2);

  k_proj1<<<LL, 256, 0, stream>>>(seq, W1, b1, xg, xgh);
  k_y<<<256, 256, 0, stream>>>(xg, W2, Ygh);
  k_outer<<<LL * 2, 128, 0, stream>>>(xgh, Ygh, b2, out);
}